// Round 1
// baseline (584.363 us; speedup 1.0000x reference)
//
#include <hip/hip_runtime.h>

// ---------------------------------------------------------------------------
// Attention block: out = SDPA(RoPE(x@wq^T), RoPE(x@wk^T), x@wv^T) @ wo^T
// B=2 S=2048 D=2048 H=16 HD=128, causal, start_pos=0.
// Strategy: bf16 MFMA everywhere (fp32 accumulate), m97-style GEMM,
// 64-row flash attention tiles.
// ---------------------------------------------------------------------------

typedef __bf16 bf16_t;
typedef __bf16 bf16x4 __attribute__((ext_vector_type(4)));
typedef __bf16 bf16x8 __attribute__((ext_vector_type(8)));
typedef float  f32x4  __attribute__((ext_vector_type(4)));

#define DEV __device__ __forceinline__

// async global->LDS, 16B per lane. LDS dest is wave-uniform base + lane*16.
DEV void async_copy16(const bf16_t* g, bf16_t* lds_uniform_base) {
    __builtin_amdgcn_global_load_lds(
        (const __attribute__((address_space(1))) void*)g,
        (__attribute__((address_space(3))) void*)lds_uniform_base,
        16, 0, 0);
}

// ---------------------------------------------------------------------------
__global__ void cast_f32_bf16(const float* __restrict__ in,
                              bf16_t* __restrict__ out, int n4) {
    int i = blockIdx.x * blockDim.x + threadIdx.x;
    if (i < n4) {
        float4 v = ((const float4*)in)[i];
        bf16x4 o = { (bf16_t)v.x, (bf16_t)v.y, (bf16_t)v.z, (bf16_t)v.w };
        ((bf16x4*)out)[i] = o;
    }
}

// ---------------------------------------------------------------------------
// C = A(MxK) * B(NxK)^T.  MODE 0: RoPE epilogue -> bf16 C (Q/K proj)
//                         MODE 1: plain bf16 C (V proj)
//                         MODE 2: fp32 C (output proj)
// 128x128 tile, BK=32, 256 threads = 4 waves, each wave 4x4 16x16 tiles.
// ---------------------------------------------------------------------------
template<int MODE>
__global__ __launch_bounds__(256)
void gemm_bt(const bf16_t* __restrict__ A, const bf16_t* __restrict__ Bm,
             void* __restrict__ Cp,
             const float* __restrict__ cosT, const float* __restrict__ sinT,
             int N, int K)
{
    __shared__ bf16_t As[128 * 32];   // unpadded: required by global_load_lds
    __shared__ bf16_t Bs[128 * 32];

    const int tid  = threadIdx.x;
    const int w    = tid >> 6;        // wave 0..3
    const int lane = tid & 63;
    const int l16  = lane & 15;
    const int quad = lane >> 4;
    const int wm   = w >> 1, wn = w & 1;
    const long m0  = (long)blockIdx.y * 128;
    const long n0  = (long)blockIdx.x * 128;

    f32x4 acc[4][4] = {};

    // staging: chunk c = i*256 + tid covers LDS elems [c*8, c*8+8)
    // = row (i*64 + tid>>2), k-offset (tid&3)*8  (row-major [128][32])
    const int srow = tid >> 2;          // 0..63
    const int soff = (tid & 3) * 8;     // k element offset
    const bf16_t* Ag = A  + (m0 + srow) * K + soff;
    const bf16_t* Bg = Bm + (n0 + srow) * K + soff;

    for (int k0 = 0; k0 < K; k0 += 32) {
        __syncthreads();
        async_copy16(Ag + k0,          As + w * 512);          // rows 0..63
        async_copy16(Ag + 64 * K + k0, As + 2048 + w * 512);   // rows 64..127
        async_copy16(Bg + k0,          Bs + w * 512);
        async_copy16(Bg + 64 * K + k0, Bs + 2048 + w * 512);
        __syncthreads();

        bf16x8 af[4], bfr[4];
        #pragma unroll
        for (int t = 0; t < 4; ++t) {
            af[t]  = *(const bf16x8*)&As[(wm * 64 + t * 16 + l16) * 32 + quad * 8];
            bfr[t] = *(const bf16x8*)&Bs[(wn * 64 + t * 16 + l16) * 32 + quad * 8];
        }
        #pragma unroll
        for (int mt = 0; mt < 4; ++mt)
            #pragma unroll
            for (int nt = 0; nt < 4; ++nt)
                acc[mt][nt] = __builtin_amdgcn_mfma_f32_16x16x32_bf16(
                    af[mt], bfr[nt], acc[mt][nt], 0, 0, 0);
    }

    // epilogue. C/D layout: col = lane&15, row = quad*4 + r
    #pragma unroll
    for (int mt = 0; mt < 4; ++mt) {
        #pragma unroll
        for (int nt = 0; nt < 4; ++nt) {
            #pragma unroll
            for (int r = 0; r < 4; ++r) {
                const long m = m0 + wm * 64 + mt * 16 + quad * 4 + r;
                const long n = n0 + wn * 64 + nt * 16 + l16;
                float v = acc[mt][nt][r];
                if (MODE == 0) {
                    // RoPE: lanes l and l^1 hold columns n (even) and n^1 (odd)
                    const float partner = __shfl_xor(v, 1);
                    const int d    = (int)n & 127;           // dim within head
                    const int fidx = ((int)m & 2047) * 64 + (d >> 1);
                    const float c = cosT[fidx], s = sinT[fidx];
                    v = ((int)n & 1) ? fmaf(partner, s, v * c)   // odd:  te*s + to*c
                                     : (v * c - partner * s);    // even: te*c - to*s
                    ((bf16_t*)Cp)[m * N + n] = (bf16_t)v;
                } else if (MODE == 1) {
                    ((bf16_t*)Cp)[m * N + n] = (bf16_t)v;
                } else {
                    ((float*)Cp)[m * N + n] = v;
                }
            }
        }
    }
}

// ---------------------------------------------------------------------------
// Flash attention, causal. Grid: (S/64 q-tiles, B*H). Block: 256 thr = 4 waves.
// Wave w owns q-rows [w*16, w*16+16) of the 64-row tile for the whole k-loop.
// ---------------------------------------------------------------------------
__global__ __launch_bounds__(256)
void flash_attn(const bf16_t* __restrict__ Q, const bf16_t* __restrict__ Kg,
                const bf16_t* __restrict__ Vg, bf16_t* __restrict__ O)
{
    constexpr int S = 2048, D = 2048, HD = 128;
    constexpr int KSTR = 136;   // 128 + 8 pad (breaks 256B-stride bank degeneracy)
    constexpr int VSTR = 72;    // 64 + 8 pad
    constexpr int PSTR = 72;
    __shared__ bf16_t Ks[64 * KSTR];    // K tile, row-major [k_row][d]
    __shared__ bf16_t Vt[128 * VSTR];   // V tile transposed [d][k_row]
    __shared__ bf16_t Ps[64 * PSTR];    // P round-trip [q_row][k_row]

    const int tid  = threadIdx.x;
    const int w    = tid >> 6, lane = tid & 63, l16 = lane & 15, quad = lane >> 4;
    const int qt   = blockIdx.x, bh = blockIdx.y;
    const int b    = bh >> 4,  h  = bh & 15;
    const int q0   = qt * 64;

    // Q fragments (A-operand layout: row = l16, k = kk*32 + quad*8 + j)
    bf16x8 qf[4];
    {
        const bf16_t* qp = Q + (long)(b * S + q0 + w * 16 + l16) * D + h * HD + quad * 8;
        #pragma unroll
        for (int kk = 0; kk < 4; ++kk) qf[kk] = *(const bf16x8*)(qp + kk * 32);
    }

    f32x4 oacc[8] = {};
    float mi[4] = { -1e30f, -1e30f, -1e30f, -1e30f };
    float li[4] = { 0.f, 0.f, 0.f, 0.f };

    const int krow = tid >> 2;          // K staging: row per 4-thread group
    const int kds  = (tid & 3) * 32;    // 32-elem column segment

    for (int kt = 0; kt <= qt; ++kt) {
        __syncthreads();
        // ---- stage K tile [64][128] -> Ks (padded) ----
        {
            const bf16_t* kp = Kg + (long)(b * S + kt * 64 + krow) * D + h * HD + kds;
            #pragma unroll
            for (int j = 0; j < 4; ++j)
                *(bf16x8*)&Ks[krow * KSTR + kds + j * 8] = *(const bf16x8*)(kp + j * 8);
            // ---- stage V tile transposed -> Vt. lane = k_row, wave = d segment.
            // writes: 64 lanes contiguous 2B -> 2-way bank alias = free.
            const bf16_t* vp = Vg + (long)(b * S + kt * 64 + lane) * D + h * HD + w * 32;
            bf16x8 vvv[4];
            #pragma unroll
            for (int j = 0; j < 4; ++j) vvv[j] = *(const bf16x8*)(vp + j * 8);
            #pragma unroll
            for (int j = 0; j < 32; ++j)
                Vt[(w * 32 + j) * VSTR + lane] = vvv[j >> 3][j & 7];
        }
        __syncthreads();

        // ---- scores: 16 q-rows x 64 k-cols per wave ----
        f32x4 sc[4];
        #pragma unroll
        for (int nt = 0; nt < 4; ++nt) {
            f32x4 c = {};
            #pragma unroll
            for (int kk = 0; kk < 4; ++kk) {
                const bf16x8 kf =
                    *(const bf16x8*)&Ks[(nt * 16 + l16) * KSTR + kk * 32 + quad * 8];
                c = __builtin_amdgcn_mfma_f32_16x16x32_bf16(qf[kk], kf, c, 0, 0, 0);
            }
            sc[nt] = c;
        }

        // scale + causal mask (diagonal tile only; earlier tiles fully valid)
        const bool diag = (kt == qt);
        #pragma unroll
        for (int nt = 0; nt < 4; ++nt) {
            #pragma unroll
            for (int r = 0; r < 4; ++r) {
                float s = sc[nt][r] * 0.08838834764831845f;   // 1/sqrt(128)
                if (diag && (nt * 16 + l16 > w * 16 + quad * 4 + r)) s = -1e30f;
                sc[nt][r] = s;
            }
        }

        // ---- online softmax, per C/D row r (row = quad*4+r, state per lane-quad)
        #pragma unroll
        for (int r = 0; r < 4; ++r) {
            float mx = fmaxf(fmaxf(sc[0][r], sc[1][r]), fmaxf(sc[2][r], sc[3][r]));
            #pragma unroll
            for (int off = 8; off >= 1; off >>= 1) mx = fmaxf(mx, __shfl_xor(mx, off));
            const float mnew  = fmaxf(mi[r], mx);
            const float alpha = __expf(mi[r] - mnew);
            mi[r] = mnew;
            float rs = 0.f;
            #pragma unroll
            for (int nt = 0; nt < 4; ++nt) {
                const float p = __expf(sc[nt][r] - mnew);
                sc[nt][r] = p;
                rs += p;
            }
            #pragma unroll
            for (int off = 8; off >= 1; off >>= 1) rs += __shfl_xor(rs, off);
            li[r] = li[r] * alpha + rs;
            #pragma unroll
            for (int nv = 0; nv < 8; ++nv) oacc[nv][r] *= alpha;
        }

        // ---- P: C/D layout -> LDS -> A-operand layout (verified m120 pattern)
        #pragma unroll
        for (int nt = 0; nt < 4; ++nt)
            #pragma unroll
            for (int r = 0; r < 4; ++r)
                Ps[(w * 16 + quad * 4 + r) * PSTR + nt * 16 + l16] = (bf16_t)sc[nt][r];

        __syncthreads();   // P write->read ordering (cheap, safe)

        // ---- O += P·V : wave w computes its 16 q-rows x 128 d-cols ----
        #pragma unroll
        for (int ks = 0; ks < 2; ++ks) {
            const bf16x8 pf =
                *(const bf16x8*)&Ps[(w * 16 + l16) * PSTR + ks * 32 + quad * 8];
            #pragma unroll
            for (int nv = 0; nv < 8; ++nv) {
                const bf16x8 vf =
                    *(const bf16x8*)&Vt[(nv * 16 + l16) * VSTR + ks * 32 + quad * 8];
                oacc[nv] = __builtin_amdgcn_mfma_f32_16x16x32_bf16(pf, vf, oacc[nv], 0, 0, 0);
            }
        }
    }

    // epilogue: O[b, q, h, d] bf16, normalized by row sum
    #pragma unroll
    for (int nv = 0; nv < 8; ++nv) {
        #pragma unroll
        for (int r = 0; r < 4; ++r) {
            const long row = (long)(b * S + q0 + w * 16 + quad * 4 + r);
            O[row * D + h * HD + nv * 16 + l16] = (bf16_t)(oacc[nv][r] / li[r]);
        }
    }
}

// ---------------------------------------------------------------------------
extern "C" void kernel_launch(void* const* d_in, const int* in_sizes, int n_in,
                              void* d_out, int out_size, void* d_ws, size_t ws_size,
                              hipStream_t stream) {
    const float* x  = (const float*)d_in[0];
    const float* wq = (const float*)d_in[1];
    const float* wk = (const float*)d_in[2];
    const float* wv = (const float*)d_in[3];
    const float* wo = (const float*)d_in[4];
    const float* fc = (const float*)d_in[5];   // (S, 64)
    const float* fs = (const float*)d_in[6];
    // d_in[7] mask (causal, reimplemented), d_in[8] start_pos (always 0): unused

    // workspace layout (bytes); O aliases xb (x-bf16 dead after V projection)
    char* ws = (char*)d_ws;
    bf16_t* xb  = (bf16_t*)(ws + 0);          // 16 MiB  (4096x2048)
    bf16_t* wqb = (bf16_t*)(ws + 16777216);   //  8 MiB
    bf16_t* wkb = (bf16_t*)(ws + 25165824);
    bf16_t* wvb = (bf16_t*)(ws + 33554432);
    bf16_t* wob = (bf16_t*)(ws + 41943040);
    bf16_t* Qb  = (bf16_t*)(ws + 50331648);   // 16 MiB each
    bf16_t* Kb  = (bf16_t*)(ws + 67108864);
    bf16_t* Vb  = (bf16_t*)(ws + 83886080);
    bf16_t* Ob  = xb;                          // alias

    cast_f32_bf16<<<8192, 256, 0, stream>>>(x,  xb,  2097152);
    cast_f32_bf16<<<4096, 256, 0, stream>>>(wq, wqb, 1048576);
    cast_f32_bf16<<<4096, 256, 0, stream>>>(wk, wkb, 1048576);
    cast_f32_bf16<<<4096, 256, 0, stream>>>(wv, wvb, 1048576);
    cast_f32_bf16<<<4096, 256, 0, stream>>>(wo, wob, 1048576);

    const dim3 gg(16, 32);   // N/128, M/128  (M = B*S = 4096, N = K = 2048)
    gemm_bt<0><<<gg, 256, 0, stream>>>(xb, wqb, Qb,    fc, fs, 2048, 2048);
    gemm_bt<0><<<gg, 256, 0, stream>>>(xb, wkb, Kb,    fc, fs, 2048, 2048);
    gemm_bt<1><<<gg, 256, 0, stream>>>(xb, wvb, Vb,    fc, fs, 2048, 2048);

    flash_attn<<<dim3(32, 32), 256, 0, stream>>>(Qb, Kb, Vb, Ob);

    gemm_bt<2><<<gg, 256, 0, stream>>>(Ob, wob, d_out, fc, fs, 2048, 2048);
}

// Round 2
// 534.483 us; speedup vs baseline: 1.0933x; 1.0933x over previous
//
#include <hip/hip_runtime.h>

// ---------------------------------------------------------------------------
// Attention block: out = SDPA(RoPE(x@wq^T), RoPE(x@wk^T), x@wv^T) @ wo^T
// B=2 S=2048 D=2048 H=16 HD=128, causal, start_pos=0.
// R2: fused QKV GEMM (N=6144, V^T epilogue), flash redesign:
//     S^T=K·Q^T trick for packed P-writes, async swizzled K/V^T staging,
//     128-row Q tiles, paired-qt load balance.
// ---------------------------------------------------------------------------

typedef __bf16 bf16_t;
typedef __bf16 bf16x4 __attribute__((ext_vector_type(4)));
typedef __bf16 bf16x8 __attribute__((ext_vector_type(8)));
typedef float  f32x4  __attribute__((ext_vector_type(4)));

#define DEV __device__ __forceinline__

DEV void async_copy16(const bf16_t* g, bf16_t* lds_uniform_base) {
    __builtin_amdgcn_global_load_lds(
        (const __attribute__((address_space(1))) void*)g,
        (__attribute__((address_space(3))) void*)lds_uniform_base,
        16, 0, 0);
}

// ---------------------------------------------------------------------------
__global__ void cast_f32_bf16(const float* __restrict__ in,
                              bf16_t* __restrict__ out, int n4) {
    int i = blockIdx.x * blockDim.x + threadIdx.x;
    if (i < n4) {
        float4 v = ((const float4*)in)[i];
        bf16x4 o = { (bf16_t)v.x, (bf16_t)v.y, (bf16_t)v.z, (bf16_t)v.w };
        ((bf16x4*)out)[i] = o;
    }
}

// ---------------------------------------------------------------------------
// Fused QKV projection: C = x(4096x2048) * W3(6144x2048)^T.
// n in [0,2048): RoPE -> Q ; [2048,4096): RoPE -> K ; [4096,6144): V^T layout.
// V^T layout: VT[((b*16+h)*128 + d)*2048 + s]  (s = seq pos within batch b)
// ---------------------------------------------------------------------------
__global__ __launch_bounds__(256)
void gemm_qkv(const bf16_t* __restrict__ A, const bf16_t* __restrict__ Bm,
              bf16_t* __restrict__ Qo, bf16_t* __restrict__ Ko,
              bf16_t* __restrict__ VTo,
              const float* __restrict__ cosT, const float* __restrict__ sinT)
{
    constexpr int K = 2048;
    __shared__ bf16_t As[128 * 32];
    __shared__ bf16_t Bs[128 * 32];

    const int tid  = threadIdx.x;
    const int w    = tid >> 6;
    const int lane = tid & 63;
    const int l16  = lane & 15;
    const int quad = lane >> 4;
    const int wm   = w >> 1, wn = w & 1;
    const long m0  = (long)blockIdx.y * 128;
    const long n0  = (long)blockIdx.x * 128;

    f32x4 acc[4][4] = {};

    const int srow = tid >> 2;
    const int soff = (tid & 3) * 8;
    const bf16_t* Ag = A  + (m0 + srow) * K + soff;
    const bf16_t* Bg = Bm + (n0 + srow) * K + soff;

    for (int k0 = 0; k0 < K; k0 += 32) {
        __syncthreads();
        async_copy16(Ag + k0,          As + w * 512);
        async_copy16(Ag + 64 * K + k0, As + 2048 + w * 512);
        async_copy16(Bg + k0,          Bs + w * 512);
        async_copy16(Bg + 64 * K + k0, Bs + 2048 + w * 512);
        __syncthreads();

        bf16x8 af[4], bfr[4];
        #pragma unroll
        for (int t = 0; t < 4; ++t) {
            af[t]  = *(const bf16x8*)&As[(wm * 64 + t * 16 + l16) * 32 + quad * 8];
            bfr[t] = *(const bf16x8*)&Bs[(wn * 64 + t * 16 + l16) * 32 + quad * 8];
        }
        #pragma unroll
        for (int mt = 0; mt < 4; ++mt)
            #pragma unroll
            for (int nt = 0; nt < 4; ++nt)
                acc[mt][nt] = __builtin_amdgcn_mfma_f32_16x16x32_bf16(
                    af[mt], bfr[nt], acc[mt][nt], 0, 0, 0);
    }

    const int region = (int)(n0 >> 11);   // block-uniform: 0=Q, 1=K, 2=V
    #pragma unroll
    for (int mt = 0; mt < 4; ++mt) {
        #pragma unroll
        for (int nt = 0; nt < 4; ++nt) {
            if (region < 2) {
                bf16_t* dst = (region == 0) ? Qo : Ko;
                #pragma unroll
                for (int r = 0; r < 4; ++r) {
                    const long m = m0 + wm * 64 + mt * 16 + quad * 4 + r;
                    const long n = n0 + wn * 64 + nt * 16 + l16;
                    float v = acc[mt][nt][r];
                    const float partner = __shfl_xor(v, 1);
                    const int d    = (int)n & 127;
                    const int fidx = ((int)m & 2047) * 64 + (d >> 1);
                    const float c = cosT[fidx], s = sinT[fidx];
                    v = ((int)n & 1) ? fmaf(partner, s, v * c)
                                     : (v * c - partner * s);
                    dst[m * 2048 + (n & 2047)] = (bf16_t)v;
                }
            } else {
                const long m  = m0 + wm * 64 + mt * 16 + quad * 4;   // r=0 base
                const int  np = (int)(n0 + wn * 64 + nt * 16 + l16) - 4096;
                bf16x4 pk;
                #pragma unroll
                for (int r = 0; r < 4; ++r) pk[r] = (bf16_t)acc[mt][nt][r];
                const int b  = (int)(m >> 11);
                const int s0 = (int)m & 2047;
                const long idx = ((long)(b * 16 + (np >> 7)) * 128 + (np & 127)) * 2048 + s0;
                *(bf16x4*)&VTo[idx] = pk;
            }
        }
    }
}

// ---------------------------------------------------------------------------
// Output projection: C = Ob(4096x2048) * wo(2048x2048)^T -> fp32 d_out
// ---------------------------------------------------------------------------
__global__ __launch_bounds__(256)
void gemm_out(const bf16_t* __restrict__ A, const bf16_t* __restrict__ Bm,
              float* __restrict__ Cp)
{
    constexpr int K = 2048, N = 2048;
    __shared__ bf16_t As[128 * 32];
    __shared__ bf16_t Bs[128 * 32];

    const int tid  = threadIdx.x;
    const int w    = tid >> 6;
    const int lane = tid & 63;
    const int l16  = lane & 15;
    const int quad = lane >> 4;
    const int wm   = w >> 1, wn = w & 1;
    const long m0  = (long)blockIdx.y * 128;
    const long n0  = (long)blockIdx.x * 128;

    f32x4 acc[4][4] = {};

    const int srow = tid >> 2;
    const int soff = (tid & 3) * 8;
    const bf16_t* Ag = A  + (m0 + srow) * K + soff;
    const bf16_t* Bg = Bm + (n0 + srow) * K + soff;

    for (int k0 = 0; k0 < K; k0 += 32) {
        __syncthreads();
        async_copy16(Ag + k0,          As + w * 512);
        async_copy16(Ag + 64 * K + k0, As + 2048 + w * 512);
        async_copy16(Bg + k0,          Bs + w * 512);
        async_copy16(Bg + 64 * K + k0, Bs + 2048 + w * 512);
        __syncthreads();

        bf16x8 af[4], bfr[4];
        #pragma unroll
        for (int t = 0; t < 4; ++t) {
            af[t]  = *(const bf16x8*)&As[(wm * 64 + t * 16 + l16) * 32 + quad * 8];
            bfr[t] = *(const bf16x8*)&Bs[(wn * 64 + t * 16 + l16) * 32 + quad * 8];
        }
        #pragma unroll
        for (int mt = 0; mt < 4; ++mt)
            #pragma unroll
            for (int nt = 0; nt < 4; ++nt)
                acc[mt][nt] = __builtin_amdgcn_mfma_f32_16x16x32_bf16(
                    af[mt], bfr[nt], acc[mt][nt], 0, 0, 0);
    }

    #pragma unroll
    for (int mt = 0; mt < 4; ++mt)
        #pragma unroll
        for (int nt = 0; nt < 4; ++nt)
            #pragma unroll
            for (int r = 0; r < 4; ++r) {
                const long m = m0 + wm * 64 + mt * 16 + quad * 4 + r;
                const long n = n0 + wn * 64 + nt * 16 + l16;
                Cp[m * N + n] = acc[mt][nt][r];
            }
}

// ---------------------------------------------------------------------------
// Flash attention, causal. Grid (16, 32): 128-row Q tiles, 64-col K tiles.
// 4 waves, wave w owns q-rows [w*32, w*32+32).
// Scores computed TRANSPOSED (S^T = K·Q^T) so C/D regs hold 4 consecutive k
// -> packed 8B P-writes; softmax reduces across quads (xor 16,32).
// K and V^T staged via global_load_lds with XOR chunk swizzle
// (conflict-free b128 reads on unpadded rows).
// qt pairing: second dispatch half reverses qt so co-resident blocks have
// complementary causal workloads.
// ---------------------------------------------------------------------------
__global__ __launch_bounds__(256)
void flash_attn(const bf16_t* __restrict__ Q, const bf16_t* __restrict__ Kg,
                const bf16_t* __restrict__ VT, bf16_t* __restrict__ O)
{
    constexpr int S = 2048, D = 2048;
    constexpr int PSTR = 72;            // 144B rows: 16B-aligned, conflict-free
    __shared__ bf16_t Ks[64 * 128];     // [k_row][d], chunk-swizzled
    __shared__ bf16_t Vt[128 * 64];     // [d][k_row], chunk-swizzled
    __shared__ bf16_t Ps[128 * PSTR];   // [q_row][k_row]

    const int tid  = threadIdx.x;
    const int w    = tid >> 6, lane = tid & 63, l16 = lane & 15, quad = lane >> 4;
    const int l7   = l16 & 7;
    const int bh   = blockIdx.y, b = bh >> 4, h = bh & 15;
    const int qt   = (blockIdx.y & 16) ? (15 - blockIdx.x) : blockIdx.x;
    const int q0   = qt * 128;

    // Q fragments (B-operand): n = q-row (w*32 + qi*16 + l16), k-dim = d
    bf16x8 qf[2][4];
    {
        const bf16_t* qp = Q + (long)(b * S + q0 + w * 32 + l16) * D + h * 128 + quad * 8;
        #pragma unroll
        for (int qi = 0; qi < 2; ++qi)
            #pragma unroll
            for (int kk = 0; kk < 4; ++kk)
                qf[qi][kk] = *(const bf16x8*)(qp + qi * 16 * D + kk * 32);
    }

    // staging offsets (chunk swizzle). K: 1024 16B-chunks, c = i*256+tid:
    //   kr=c>>4, cs=c&15, global chunk cc = (cs&8)|((cs&7)^(kr&7))
    // V^T: 1024 chunks, d=c>>3, cs=c&7, cc = cs^(d&7)
    int koff[4], vof[4];
    #pragma unroll
    for (int i = 0; i < 4; ++i) {
        const int c  = i * 256 + tid;
        const int kr = c >> 4, cs = c & 15;
        const int cc = (cs & 8) | ((cs & 7) ^ (kr & 7));
        koff[i] = kr * D + cc * 8;
        const int d  = c >> 3, vs = c & 7;
        vof[i] = d * S + (vs ^ (d & 7)) * 8;
    }
    const bf16_t* Kbase = Kg + (long)b * S * D + h * 128;
    const bf16_t* Vbase = VT + (long)bh * 128 * S;

    f32x4 oacc[2][8] = {};
    float mi[2] = { -1e30f, -1e30f };
    float li[2] = { 0.f, 0.f };
    const float SC = 0.08838834764831845f * 1.44269504088896340f; // 1/sqrt(128)*log2(e)

    const int nkt = 2 * qt + 2;
    for (int kt = 0; kt < nkt; ++kt) {
        __syncthreads();
        {
            const bf16_t* kp = Kbase + (long)kt * 64 * D;
            const bf16_t* vp = Vbase + kt * 64;
            #pragma unroll
            for (int i = 0; i < 4; ++i) {
                async_copy16(kp + koff[i], Ks + i * 2048 + w * 512);
                async_copy16(vp + vof[i], Vt + i * 2048 + w * 512);
            }
        }
        __syncthreads();

        // skip fully-masked wave tiles (keeps softmax well-defined too)
        if (kt * 64 <= q0 + w * 32 + 31) {
            // ---- S^T = K·Q^T : A = K-frag (m = k-row), B = Q-frag (n = q)
            f32x4 sc[4][2] = {};
            #pragma unroll
            for (int kk = 0; kk < 4; ++kk) {
                #pragma unroll
                for (int mt = 0; mt < 4; ++mt) {
                    const int cc = kk * 4 + quad;
                    const bf16x8 kf = *(const bf16x8*)
                        &Ks[(mt * 16 + l16) * 128 + ((cc & 8) | ((cc & 7) ^ l7)) * 8];
                    sc[mt][0] = __builtin_amdgcn_mfma_f32_16x16x32_bf16(
                        kf, qf[0][kk], sc[mt][0], 0, 0, 0);
                    sc[mt][1] = __builtin_amdgcn_mfma_f32_16x16x32_bf16(
                        kf, qf[1][kk], sc[mt][1], 0, 0, 0);
                }
            }

            // ---- scale + causal mask (lane: k = mt*16+quad*4+r, q = qi*16+l16)
            const bool tail = (kt * 64 + 63 > q0 + w * 32);   // wave-uniform
            #pragma unroll
            for (int qi = 0; qi < 2; ++qi) {
                const int qg = q0 + w * 32 + qi * 16 + l16;
                #pragma unroll
                for (int mt = 0; mt < 4; ++mt)
                    #pragma unroll
                    for (int r = 0; r < 4; ++r) {
                        const int kg = kt * 64 + mt * 16 + quad * 4 + r;
                        const float sv = sc[mt][qi][r] * SC;
                        sc[mt][qi][r] = (tail && kg > qg) ? -1e30f : sv;
                    }
            }

            // ---- online softmax (base-2), state per q (indexed by l16)
            #pragma unroll
            for (int qi = 0; qi < 2; ++qi) {
                float mx = -1e30f;
                #pragma unroll
                for (int mt = 0; mt < 4; ++mt)
                    #pragma unroll
                    for (int r = 0; r < 4; ++r) mx = fmaxf(mx, sc[mt][qi][r]);
                mx = fmaxf(mx, __shfl_xor(mx, 16));
                mx = fmaxf(mx, __shfl_xor(mx, 32));
                const float mnew  = fmaxf(mi[qi], mx);
                const float alpha = exp2f(mi[qi] - mnew);
                mi[qi] = mnew;
                float rs = 0.f;
                #pragma unroll
                for (int mt = 0; mt < 4; ++mt) {
                    bf16x4 pk;
                    #pragma unroll
                    for (int r = 0; r < 4; ++r) {
                        const float p = exp2f(sc[mt][qi][r] - mnew);
                        rs += p;
                        pk[r] = (bf16_t)p;
                    }
                    *(bf16x4*)&Ps[(w * 32 + qi * 16 + l16) * PSTR + mt * 16 + quad * 4] = pk;
                }
                rs += __shfl_xor(rs, 16);
                rs += __shfl_xor(rs, 32);
                li[qi] = li[qi] * alpha + rs;
                #pragma unroll
                for (int r = 0; r < 4; ++r) {
                    const float ar = __shfl(alpha, quad * 4 + r);
                    #pragma unroll
                    for (int nv = 0; nv < 8; ++nv) oacc[qi][nv][r] *= ar;
                }
            }

            // ---- O += P·V^T : A = P (m=q), B = V^T (n=d); vf shared across qi
            #pragma unroll
            for (int ks = 0; ks < 2; ++ks) {
                const bf16x8 pf0 = *(const bf16x8*)
                    &Ps[(w * 32 + l16) * PSTR + ks * 32 + quad * 8];
                const bf16x8 pf1 = *(const bf16x8*)
                    &Ps[(w * 32 + 16 + l16) * PSTR + ks * 32 + quad * 8];
                #pragma unroll
                for (int nv = 0; nv < 8; ++nv) {
                    const bf16x8 vf = *(const bf16x8*)
                        &Vt[(nv * 16 + l16) * 64 + (((ks * 4 + quad) ^ l7)) * 8];
                    oacc[0][nv] = __builtin_amdgcn_mfma_f32_16x16x32_bf16(
                        pf0, vf, oacc[0][nv], 0, 0, 0);
                    oacc[1][nv] = __builtin_amdgcn_mfma_f32_16x16x32_bf16(
                        pf1, vf, oacc[1][nv], 0, 0, 0);
                }
            }
        }
    }

    // epilogue: O[b, q, h, d], rows normalized by li (held at lane l16 = q)
    #pragma unroll
    for (int qi = 0; qi < 2; ++qi)
        #pragma unroll
        for (int r = 0; r < 4; ++r) {
            const float lr  = __shfl(li[qi], quad * 4 + r);
            const float inv = 1.0f / lr;
            const long row  = (long)(b * S + q0 + w * 32 + qi * 16 + quad * 4 + r);
            #pragma unroll
            for (int nv = 0; nv < 8; ++nv)
                O[row * D + h * 128 + nv * 16 + l16] = (bf16_t)(oacc[qi][nv][r] * inv);
        }
}

// ---------------------------------------------------------------------------
extern "C" void kernel_launch(void* const* d_in, const int* in_sizes, int n_in,
                              void* d_out, int out_size, void* d_ws, size_t ws_size,
                              hipStream_t stream) {
    const float* x  = (const float*)d_in[0];
    const float* wq = (const float*)d_in[1];
    const float* wk = (const float*)d_in[2];
    const float* wv = (const float*)d_in[3];
    const float* wo = (const float*)d_in[4];
    const float* fc = (const float*)d_in[5];
    const float* fs = (const float*)d_in[6];

    // ws layout: xb 0..16M | W3 (wq,wk,wv bf16 contiguous) 16M..40M |
    //            wob 40M..48M | Qb 48M | Kb 64M | VTb 80M  (total 96M)
    char* ws = (char*)d_ws;
    bf16_t* xb  = (bf16_t*)(ws + 0);
    bf16_t* W3  = (bf16_t*)(ws + (16l << 20));
    bf16_t* wqb = W3;
    bf16_t* wkb = (bf16_t*)(ws + (24l << 20));
    bf16_t* wvb = (bf16_t*)(ws + (32l << 20));
    bf16_t* wob = (bf16_t*)(ws + (40l << 20));
    bf16_t* Qb  = (bf16_t*)(ws + (48l << 20));
    bf16_t* Kb  = (bf16_t*)(ws + (64l << 20));
    bf16_t* VTb = (bf16_t*)(ws + (80l << 20));
    bf16_t* Ob  = xb;   // x dead after QKV projection

    cast_f32_bf16<<<8192, 256, 0, stream>>>(x,  xb,  2097152);
    cast_f32_bf16<<<4096, 256, 0, stream>>>(wq, wqb, 1048576);
    cast_f32_bf16<<<4096, 256, 0, stream>>>(wk, wkb, 1048576);
    cast_f32_bf16<<<4096, 256, 0, stream>>>(wv, wvb, 1048576);
    cast_f32_bf16<<<4096, 256, 0, stream>>>(wo, wob, 1048576);

    gemm_qkv<<<dim3(48, 32), 256, 0, stream>>>(xb, W3, Qb, Kb, VTb, fc, fs);

    flash_attn<<<dim3(16, 32), 256, 0, stream>>>(Qb, Kb, VTb, Ob);

    gemm_out<<<dim3(16, 32), 256, 0, stream>>>(Ob, wob, (float*)d_out);
}